// Round 18
// baseline (142.653 us; speedup 1.0000x reference)
//
#include <hip/hip_runtime.h>
#include <hip/hip_bf16.h>
#include <math.h>

#define PI_F 3.14159265358979323846f

typedef __attribute__((ext_vector_type(8))) short short8v;   // 8 bf16 (4 VGPR)
typedef __attribute__((ext_vector_type(4))) float f32x4;

__device__ __forceinline__ short f2bf(float x) {
    return __builtin_bit_cast(short, __float2bfloat16(x));
}
__device__ __forceinline__ float bf2f(unsigned short u) {
    return __uint_as_float(((unsigned)u) << 16);
}
__device__ __forceinline__ int pack_bf2(float a, float b) {
    return (int)(unsigned short)f2bf(a) | ((int)(unsigned short)f2bf(b) << 16);
}

// ---------------- workspace layout (float slots) — round-13 proven ----------------
static const size_t WS_WA     = 0;        // [2][64][4] f32
static const size_t WS_BA     = 512;      // [2][4] f32
static const size_t WS_BM     = 520;      // [2][128] f32
static const size_t WS_WMF    = 776;      // [2][8][2][64][8] bf16 = 16384
static const size_t WS_WSHF   = 8968;     // [8][64][8] bf16 = 4096
static const size_t WS_QKF    = 11016;    // [4][64][8] bf16 = 2048
static const size_t WS_WVF    = 12040;    // [4][8][64][8] bf16 = 16384
static const size_t WS_WOF    = 20232;    // [4][8][64][8] bf16 = 16384
static const size_t WS_COUNTS = 28424;    // [8192] int + [1] done (pad slot)
static const size_t WS_OFFS   = 36624;    // [8193] int (+pad)
static const size_t WS_CURSOR = 44824;    // [8192] int
static const size_t WS_PACKED = 53016;    // [E] int (src | dst<<16)
static const size_t WS_LK     = 315160;   // [N][4] f32
static const size_t WS_EDP    = 479000;   // [E][4] f32 {p0..p3}
static const size_t WS_EDG    = 1527576;  // [E][4] f32 {ux,uy,uz,xn}
static const size_t WS_VB     = 2576152;  // [N][128] bf16
static const size_t WS_OUTPRE = 5197592;  // [NQ][128] f32
// end 5721880 slots = 22.89 MB (proven in rounds 6-7, 10, 13, 17)

// ---------------------------------------------------------------
// Block 0: fold QK/Wa/ba/bm, emit QKF frags.
// Blocks 1..208: format WmF / WshF / WVF / WOF fragments.
// Blocks 209..240: zero counts + done (replaces in-graph hipMemsetAsync).
// B-frag column permutation: physical col c = (lane&15)*8 + ct.
__global__ __launch_bounds__(256) void k_prepfmt(
    const float* b_dst, const float* Wq, const float* Wk,
    const float* W_rad0, const float* b_rad0,
    const float* W_rad1, const float* b_rad1,
    const float* W_msg, const float* W_alpha, const float* Wv,
    const float* Wo, const float* W_sh,
    float* Wa, float* ba, float* bm,
    short* WmF, short* WshF, short* QKF, short* WVF, short* WOF,
    int* counts, int nkey) {
    __shared__ float qs_s[128];
    __shared__ float qk_s[512];
    int t = threadIdx.x;
    int b = blockIdx.x;
    if (b == 0) {
        if (t < 128) {
            float acc = 0.f;
            for (int c = 0; c < 128; ++c) acc += b_dst[c] * Wq[c * 128 + t];
            qs_s[t] = acc;
        }
        __syncthreads();
        if (t < 128) {
            const float invs = 0.17677669529663687f; // 1/sqrt(32)
            for (int h = 0; h < 4; ++h) {
                float acc = 0.f;
                for (int d = 0; d < 32; ++d)
                    acc += Wk[t * 128 + h * 32 + d] * qs_s[h * 32 + d];
                qk_s[t * 4 + h] = acc * invs;
            }
        }
        for (int idx = t; idx < 512; idx += 256) {
            int s = idx >> 8, i = (idx >> 2) & 63, h = idx & 3;
            const float* Wr = s ? W_rad1 : W_rad0;
            float acc = 0.f;
            for (int u = 0; u < 64; ++u) acc += Wr[i * 64 + u] * W_alpha[u * 4 + h];
            Wa[idx] = acc;
        }
        if (t < 8) {
            int s = t >> 2, h = t & 3;
            const float* br = s ? b_rad1 : b_rad0;
            float acc = 0.f;
            for (int u = 0; u < 64; ++u) acc += br[u] * W_alpha[u * 4 + h];
            ba[t] = acc;
        }
        {
            int s = t >> 7, c = t & 127;
            const float* br = s ? b_rad1 : b_rad0;
            float acc = 0.f;
            for (int u = 0; u < 64; ++u) acc += br[u] * W_msg[u * 128 + c];
            bm[t] = acc;
        }
        __syncthreads();
        for (int idx = t; idx < 2048; idx += 256) {
            int j = idx & 7, lane = (idx >> 3) & 63, kh = idx >> 9;
            int k = kh * 32 + ((lane >> 4) << 3) + j;
            int col = lane & 15;
            QKF[idx] = f2bf(col < 4 ? qk_s[k * 4 + col] : 0.f);
        }
    } else if (b <= 208) {
        int item = (b - 1) * 256 + t;   // 0..53247
        if (item < 16384) {
            int j = item & 7, lane = (item >> 3) & 63, kh = (item >> 9) & 1;
            int ct = (item >> 10) & 7, sid = item >> 13;
            int k = kh * 32 + ((lane >> 4) << 3) + j;
            int c = (lane & 15) * 8 + ct;        // permuted
            const float* Wr = sid ? W_rad1 : W_rad0;
            float acc = 0.f;
            for (int u = 0; u < 64; ++u) acc += Wr[k * 64 + u] * W_msg[u * 128 + c];
            WmF[item] = f2bf(acc);
        } else if (item < 20480) {
            int i2 = item - 16384;
            int j = i2 & 7, lane = (i2 >> 3) & 63, ct = (i2 >> 9) & 7;
            int k = ((lane >> 4) << 3) + j;
            int c = (lane & 15) * 8 + ct;        // permuted
            WshF[i2] = f2bf(k < 9 ? W_sh[k * 128 + c] : 0.f);
        } else if (item < 36864) {
            int i2 = item - 20480;   // [kh][ct][lane][j]
            int j = i2 & 7, lane = (i2 >> 3) & 63, ct = (i2 >> 9) & 7, kh = (i2 >> 12) & 3;
            int k = kh * 32 + ((lane >> 4) << 3) + j;
            int c = (lane & 15) * 8 + ct;        // permuted
            WVF[i2] = f2bf(Wv[k * 128 + c]);
        } else {
            int i2 = item - 36864;
            int j = i2 & 7, lane = (i2 >> 3) & 63, ct = (i2 >> 9) & 7, kh = (i2 >> 12) & 3;
            int k = kh * 32 + ((lane >> 4) << 3) + j;
            int c = (lane & 15) * 8 + ct;        // permuted
            WOF[i2] = f2bf(Wo[k * 128 + c]);
        }
    } else {
        int idx = (b - 209) * 256 + t;
        if (idx < nkey + 1) counts[idx] = 0;    // +1 zeroes the done slot
    }
}

// ---------------------------------------------------------------
// MFMA GEMM with permuted B: out[row][m*8+ct]; vectorized stores.
// Optional lk = A @ QK. Blocks past the GEMM grid run the edge histogram;
// the LAST hist block to finish also performs the exclusive scan
// (offsets/cursor). Block-level acq-rel done counter; per-block atomics are
// drained by __syncthreads() (compiler emits vmcnt(0) before s_barrier).
template <typename OUT, bool LK>
__global__ __launch_bounds__(256) void k_mgemm(
    const float* A, const short* WF, const float* bias, OUT* out,
    float* lk, const short* QKF, int M,
    const int* edge_dst, const int* scale_id, int* counts, int* done,
    int* offsets, int* cursor, int E, int NQr, int nkey, int histBlocks) {
    int gb = (M + 63) >> 6;            // GEMM blocks
    if ((int)blockIdx.x >= gb) {
        __shared__ int amLast;
        __shared__ int sdata[256];
        int t = threadIdx.x;
        int e = ((int)blockIdx.x - gb) * 256 + t;
        if (e < E) atomicAdd(&counts[scale_id[e] * NQr + edge_dst[e]], 1);
        __syncthreads();   // drains this block's atomics (vmcnt(0) before barrier)
        if (t == 0)
            amLast = (__hip_atomic_fetch_add(done, 1, __ATOMIC_ACQ_REL,
                                             __HIP_MEMORY_SCOPE_AGENT)
                      == histBlocks - 1);
        __syncthreads();
        if (!amLast) return;
        // ---- exclusive scan over counts (agent-scope atomic loads) ----
        int chunk = (nkey + 255) / 256;
        int sum = 0;
        for (int i = 0; i < chunk; ++i) {
            int idx = t * chunk + i;
            sum += (idx < nkey)
                ? __hip_atomic_load(&counts[idx], __ATOMIC_RELAXED,
                                    __HIP_MEMORY_SCOPE_AGENT)
                : 0;
        }
        sdata[t] = sum;
        __syncthreads();
        for (int off = 1; off < 256; off <<= 1) {
            int v = (t >= off) ? sdata[t - off] : 0;
            __syncthreads();
            sdata[t] += v;
            __syncthreads();
        }
        int run = sdata[t] - sum;
        for (int i = 0; i < chunk; ++i) {
            int idx = t * chunk + i;
            if (idx < nkey) {
                int c = __hip_atomic_load(&counts[idx], __ATOMIC_RELAXED,
                                          __HIP_MEMORY_SCOPE_AGENT);
                offsets[idx] = run;
                cursor[idx] = run;
                run += c;
            }
        }
        if (t == 255) offsets[nkey] = sdata[255];
        return;
    }
    int t = threadIdx.x;
    int w = t >> 6, lane = t & 63;
    int m = lane & 15, grp = lane >> 4;
    int row0 = (blockIdx.x * 4 + w) * 16;
    if (row0 >= M) return;

    short8v a[4];
#pragma unroll
    for (int kh = 0; kh < 4; ++kh) {
        const float* ap = &A[(size_t)(row0 + m) * 128 + kh * 32 + grp * 8];
        float4 f0 = *(const float4*)ap;
        float4 f1 = *(const float4*)(ap + 4);
        a[kh][0] = f2bf(f0.x); a[kh][1] = f2bf(f0.y);
        a[kh][2] = f2bf(f0.z); a[kh][3] = f2bf(f0.w);
        a[kh][4] = f2bf(f1.x); a[kh][5] = f2bf(f1.y);
        a[kh][6] = f2bf(f1.z); a[kh][7] = f2bf(f1.w);
    }
    if constexpr (LK) {
        f32x4 cl = {0.f, 0.f, 0.f, 0.f};
#pragma unroll
        for (int kh = 0; kh < 4; ++kh) {
            short8v qb = *(const short8v*)&QKF[(kh * 64 + lane) * 8];
            cl = __builtin_amdgcn_mfma_f32_16x16x32_bf16(a[kh], qb, cl, 0, 0, 0);
        }
        if (m < 4) {
#pragma unroll
            for (int r = 0; r < 4; ++r)
                lk[(size_t)(row0 + grp * 4 + r) * 4 + m] = cl[r];
        }
    }
    f32x4 c8[8];
#pragma unroll
    for (int ct = 0; ct < 8; ++ct) {
        f32x4 c = {0.f, 0.f, 0.f, 0.f};
#pragma unroll
        for (int kh = 0; kh < 4; ++kh) {
            short8v bf = *(const short8v*)&WF[((kh * 8 + ct) * 64 + lane) * 8];
            c = __builtin_amdgcn_mfma_f32_16x16x32_bf16(a[kh], bf, c, 0, 0, 0);
        }
        c8[ct] = c;
    }
    if constexpr (sizeof(OUT) == 2) {
#pragma unroll
        for (int r = 0; r < 4; ++r) {
            int row = row0 + grp * 4 + r;
            int4 sv;
            sv.x = pack_bf2(c8[0][r], c8[1][r]);
            sv.y = pack_bf2(c8[2][r], c8[3][r]);
            sv.z = pack_bf2(c8[4][r], c8[5][r]);
            sv.w = pack_bf2(c8[6][r], c8[7][r]);
            *(int4*)&out[(size_t)row * 128 + m * 8] = sv;
        }
    } else {
        float4 b0 = make_float4(0.f, 0.f, 0.f, 0.f), b1 = b0;
        if (bias) {
            b0 = *(const float4*)&bias[m * 8];
            b1 = *(const float4*)&bias[m * 8 + 4];
        }
#pragma unroll
        for (int r = 0; r < 4; ++r) {
            int row = row0 + grp * 4 + r;
            float4 o0 = make_float4(c8[0][r] + b0.x, c8[1][r] + b0.y,
                                    c8[2][r] + b0.z, c8[3][r] + b0.w);
            float4 o1 = make_float4(c8[4][r] + b1.x, c8[5][r] + b1.y,
                                    c8[6][r] + b1.z, c8[7][r] + b1.w);
            *(float4*)&out[(size_t)row * 128 + m * 8] = o0;
            *(float4*)&out[(size_t)row * 128 + m * 8 + 4] = o1;
        }
    }
}

// ---------------------------------------------------------------
// Fused scatter + per-edge geometry/softmax-numerator pass.
__global__ __launch_bounds__(256) void k_scatter_edge(
    const int* edge_src, const int* edge_dst, const int* scale_id,
    const float* qc, const float* nc, const float* lk,
    const float* WaB, const float* baB, int* cursor,
    int* packed, float* edP, float* edG, int E, int NQr) {
    __shared__ float WaS[512];
    __shared__ float baS[8];
    int t = threadIdx.x;
    for (int i = t; i < 512; i += 256) WaS[i] = WaB[i];
    if (t < 8) baS[t] = baB[t];
    __syncthreads();
    int e = blockIdx.x * 256 + t;
    if (e >= E) return;
    int src = edge_src[e], dst = edge_dst[e], sid = scale_id[e];
    int pos = atomicAdd(&cursor[sid * NQr + dst], 1);

    float qx = qc[dst * 3 + 0], qy = qc[dst * 3 + 1], qz = qc[dst * 3 + 2];
    float vx = nc[src * 3 + 0] - qx;
    float vy = nc[src * 3 + 1] - qy;
    float vz = nc[src * 3 + 2] - qz;
    float r = sqrtf(vx * vx + vy * vy + vz * vz + 1e-12f);
    float rinv = 1.0f / r;
    float ux = vx * rinv, uy = vy * rinv, uz = vz * rinv;

    float roff = sid ? 0.2f : 0.1f;
    float rdiv = sid ? (1.0f / 3.8f) : (1.0f / 1.9f);
    float xn = (r - roff) * rdiv;
    float su = fminf(fmaxf((xn - 0.8f) * 5.0f, 0.0f), 1.0f);
    float soft = 0.5f * (1.0f + __cosf(PI_F * su));

    float4 lkv = *(const float4*)&lk[(size_t)src * 4];

    const float qs = 64.f / 63.f;
    const float Qc = __expf(-qs * qs);
    const float* Wrow = WaS + sid * 256;
    float a0 = 0.f, a1 = 0.f, a2 = 0.f, a3 = 0.f;
#pragma unroll
    for (int ch = 0; ch < 8; ++ch) {
        float d = (xn - (float)(ch * 8) * (1.0f / 63.0f)) * 64.0f;
        float g = __expf(-0.5f * d * d);
        float tt = __expf(fminf(qs * d - 0.5f * qs * qs, 60.f));
#pragma unroll
        for (int j = 0; j < 8; ++j) {
            float4 wa = *(const float4*)&Wrow[(ch * 8 + j) * 4];
            a0 = fmaf(g, wa.x, a0);
            a1 = fmaf(g, wa.y, a1);
            a2 = fmaf(g, wa.z, a2);
            a3 = fmaf(g, wa.w, a3);
            g *= tt; tt *= Qc;
        }
    }
    float p0 = __expf(lkv.x + soft * a0 + baS[sid * 4 + 0]);
    float p1 = __expf(lkv.y + soft * a1 + baS[sid * 4 + 1]);
    float p2 = __expf(lkv.z + soft * a2 + baS[sid * 4 + 2]);
    float p3 = __expf(lkv.w + soft * a3 + baS[sid * 4 + 3]);
    packed[pos] = src | (dst << 16);
    *(float4*)&edP[(size_t)pos * 4] = make_float4(p0, p1, p2, p3);
    *(float4*)&edG[(size_t)pos * 4] = make_float4(ux, uy, uz, xn);
}

// ---------------------------------------------------------------
// g-fragment via multiply-chain (2 exp per 8 centers).
__device__ __forceinline__ short8v gchain(float xn, int k0, float soft, float Qc) {
    const float qs = 64.f / 63.f;
    float d = (xn - (float)k0 * (1.0f / 63.0f)) * 64.0f;
    float g = __expf(-0.5f * d * d);
    float tt = __expf(fminf(qs * d - 0.5f * qs * qs, 60.f));
    short8v rr;
#pragma unroll
    for (int j = 0; j < 8; ++j) {
        rr[j] = f2bf(g * soft);
        g *= tt; tt *= Qc;
    }
    return rr;
}

// MFMA edge aggregation: one WAVE per (dst,sid) key, 2-stage pipeline
// (packed/edP/edG two tiles ahead; V one tile ahead). The two sid-waves of
// a dst share a block and combine via one LDS pair-sum. Grid = NQ/2.
__global__ __launch_bounds__(256) void k_main10(
    const int* offsets, const int* packed, const float* edP, const float* edG,
    const unsigned short* Vu, const float* bm, const short* WmF, const short* WshF,
    float* out_pre, int NQr) {
    __shared__ float part[4][132];
    int t = threadIdx.x;
    int w = t >> 6, lane = t & 63;
    int sid = w & 1;
    int dst = blockIdx.x * 2 + (w >> 1);
    int m = lane & 15, grp = lane >> 4;
    int h = m >> 2;

    int key = sid * NQr + dst;
    int s0 = offsets[key], s1 = offsets[key + 1];
    int nt = (s1 - s0 + 15) >> 4;

    float acc[8];
#pragma unroll
    for (int i = 0; i < 8; ++i) acc[i] = 0.f;
    float den = 0.f;

    float4 bm0 = *(const float4*)&bm[sid * 128 + m * 8];
    float4 bm1 = *(const float4*)&bm[sid * 128 + m * 8 + 4];
    float bmv[8] = {bm0.x, bm0.y, bm0.z, bm0.w, bm1.x, bm1.y, bm1.z, bm1.w};
    const short* wmp = WmF + sid * 8192;

    const float qs = 64.f / 63.f;
    const float Qc = __expf(-qs * qs);
    const float s3 = 1.7320508075688772f, s15 = 3.872983346207417f, s5 = 2.23606797749979f;

    if (nt > 0) {
        auto loadA = [&](int tl, int (&srcs)[4], float (&ph)[4], float4& G4) {
            int q0 = s0 + tl * 16;
            int posA = q0 + m; if (posA >= s1) posA = s1 - 1;
            G4 = *(const float4*)&edG[(size_t)posA * 4];
#pragma unroll
            for (int r = 0; r < 4; ++r) {
                int pos = q0 + grp * 4 + r;
                bool valid = pos < s1;
                if (!valid) pos = s1 - 1;
                srcs[r] = packed[pos] & 0xFFFF;
                float p = edP[(size_t)pos * 4 + h];
                ph[r] = valid ? p : 0.f;
            }
        };
        auto loadV = [&](const int (&srcs)[4], int4 (&vv)[4]) {
#pragma unroll
            for (int r = 0; r < 4; ++r)
                vv[r] = *(const int4*)&Vu[(size_t)srcs[r] * 128 + m * 8];
        };

        int srcsA[4], srcsB[4], srcsC[4];
        float phA[4], phB[4], phC[4];
        float4 gA, gB, gC;
        int4 vA[4], vB[4];

        loadA(0, srcsA, phA, gA);
        loadV(srcsA, vA);
        if (nt > 1) loadA(1, srcsB, phB, gB);

        for (int tl = 0; tl < nt; ++tl) {
            if (tl + 1 < nt) loadV(srcsB, vB);
            if (tl + 2 < nt) loadA(tl + 2, srcsC, phC, gC);

            // ---- compute current tile ----
            int wds[4][4];
#pragma unroll
            for (int r = 0; r < 4; ++r) {
                wds[r][0] = vA[r].x; wds[r][1] = vA[r].y;
                wds[r][2] = vA[r].z; wds[r][3] = vA[r].w;
            }
            den += phA[0] + phA[1] + phA[2] + phA[3];

            float xn = gA.w;
            float su = fminf(fmaxf((xn - 0.8f) * 5.0f, 0.0f), 1.0f);
            float soft = 0.5f * (1.0f + __cosf(PI_F * su));
            short8v aG0 = gchain(xn, grp * 8, soft, Qc);
            short8v aG1 = gchain(xn, 32 + grp * 8, soft, Qc);

            float ux = gA.x, uy = gA.y, uz = gA.z;
            float sh[9];
            sh[0] = 1.f; sh[1] = s3 * ux; sh[2] = s3 * uy; sh[3] = s3 * uz;
            sh[4] = s15 * ux * uy; sh[5] = s15 * uy * uz;
            sh[6] = 0.5f * s5 * (3.f * uz * uz - 1.f);
            sh[7] = s15 * ux * uz; sh[8] = 0.5f * s15 * (ux * ux - uy * uy);
            short8v aS;
#pragma unroll
            for (int j = 0; j < 8; ++j) {
                float v = (grp == 0) ? sh[j] : ((grp == 1 && j == 0) ? sh[8] : 0.f);
                aS[j] = f2bf(v);
            }

#pragma unroll
            for (int ct = 0; ct < 8; ++ct) {
                short8v b0 = *(const short8v*)&wmp[((ct * 2 + 0) * 64 + lane) * 8];
                short8v b1 = *(const short8v*)&wmp[((ct * 2 + 1) * 64 + lane) * 8];
                short8v bS = *(const short8v*)&WshF[(ct * 64 + lane) * 8];
                f32x4 cms = {bmv[ct], bmv[ct], bmv[ct], bmv[ct]};   // seed with bm
                cms = __builtin_amdgcn_mfma_f32_16x16x32_bf16(aG0, b0, cms, 0, 0, 0);
                cms = __builtin_amdgcn_mfma_f32_16x16x32_bf16(aG1, b1, cms, 0, 0, 0);
                f32x4 csh = {0.f, 0.f, 0.f, 0.f};
                csh = __builtin_amdgcn_mfma_f32_16x16x32_bf16(aS, bS, csh, 0, 0, 0);
#pragma unroll
                for (int r = 0; r < 4; ++r) {
                    int wd = wds[r][ct >> 1];
                    unsigned short vu = (ct & 1) ? (unsigned short)(wd >> 16)
                                                 : (unsigned short)(wd & 0xFFFF);
                    float vf = bf2f(vu);
                    float ve = fmaf(vf, cms[r], csh[r]);
                    acc[ct] = fmaf(phA[r], ve, acc[ct]);
                }
            }

            // ---- rotate pipeline ----
            gA = gB; gB = gC;
#pragma unroll
            for (int r = 0; r < 4; ++r) {
                phA[r] = phB[r]; phB[r] = phC[r];
                srcsB[r] = srcsC[r];
                vA[r] = vB[r];
            }
        }
    }

    // ---- reduce over grp within wave ----
#pragma unroll
    for (int i = 0; i < 8; ++i) {
        acc[i] += __shfl_xor(acc[i], 16);
        acc[i] += __shfl_xor(acc[i], 32);
    }
    den += __shfl_xor(den, 16);
    den += __shfl_xor(den, 32);
    if (lane < 16) {
#pragma unroll
        for (int ct = 0; ct < 8; ++ct) part[w][m * 8 + ct] = acc[ct];
        if ((m & 3) == 0) part[w][128 + h] = den;
    }
    __syncthreads();

    // ---- combine the two sid-waves of each dst, divide, store ----
    {
        int which = t >> 7;
        int col = t & 127;
        int d2 = blockIdx.x * 2 + which;
        if (d2 < NQr) {
            int hh = col >> 5;
            float s = part[2 * which][col] + part[2 * which + 1][col];
            float d = part[2 * which][128 + hh] + part[2 * which + 1][128 + hh];
            out_pre[(size_t)d2 * 128 + col] = s / (d + 1e-9f);
        }
    }
}

// ---------------------------------------------------------------
extern "C" void kernel_launch(void* const* d_in, const int* in_sizes, int n_in,
                              void* d_out, int out_size, void* d_ws, size_t ws_size,
                              hipStream_t stream) {
    const float* query_coord = (const float*)d_in[0];
    const float* node_feature = (const float*)d_in[1];
    const float* node_coord = (const float*)d_in[2];
    const int* edge_src = (const int*)d_in[3];
    const int* edge_dst = (const int*)d_in[4];
    const int* scale_id = (const int*)d_in[5];
    const float* b_dst = (const float*)d_in[6];
    const float* Wq = (const float*)d_in[7];
    const float* Wk = (const float*)d_in[8];
    const float* Wv = (const float*)d_in[9];
    const float* Wo = (const float*)d_in[10];
    const float* bo = (const float*)d_in[11];
    const float* W_rad0 = (const float*)d_in[12];
    const float* b_rad0 = (const float*)d_in[13];
    const float* W_rad1 = (const float*)d_in[14];
    const float* b_rad1 = (const float*)d_in[15];
    const float* W_msg = (const float*)d_in[16];
    const float* W_sh = (const float*)d_in[17];
    const float* W_alpha = (const float*)d_in[18];
    (void)n_in; (void)ws_size; (void)out_size;

    int NQr = in_sizes[0] / 3;      // 4096
    int Nn = in_sizes[1] / 128;     // 40960
    int E = in_sizes[3];            // 262144
    int nkey = NQr * 2;

    float* ws = (float*)d_ws;
    float* Wa = ws + WS_WA;
    float* ba = ws + WS_BA;
    float* bm = ws + WS_BM;
    short* WmF = (short*)(ws + WS_WMF);
    short* WshF = (short*)(ws + WS_WSHF);
    short* QKF = (short*)(ws + WS_QKF);
    short* WVF = (short*)(ws + WS_WVF);
    short* WOF = (short*)(ws + WS_WOF);
    int* counts = (int*)(ws + WS_COUNTS);
    int* offsets = (int*)(ws + WS_OFFS);
    int* cursor = (int*)(ws + WS_CURSOR);
    int* packed = (int*)(ws + WS_PACKED);
    float* lk = ws + WS_LK;
    float* edP = ws + WS_EDP;
    float* edG = ws + WS_EDG;
    unsigned short* Vb = (unsigned short*)(ws + WS_VB);
    float* out_pre = ws + WS_OUTPRE;
    float* out = (float*)d_out;
    int* done = counts + nkey;      // pad slot, zeroed by k_prepfmt

    int zeroBlocks = (nkey + 1 + 255) / 256;        // 33
    int histBlocks = (E + 255) / 256;               // 1024
    int gemmVBlocks = (Nn + 63) / 64;               // 640
    hipLaunchKernelGGL(k_prepfmt, dim3(209 + zeroBlocks), dim3(256), 0, stream,
                       b_dst, Wq, Wk, W_rad0, b_rad0, W_rad1, b_rad1, W_msg, W_alpha,
                       Wv, Wo, W_sh, Wa, ba, bm, WmF, WshF, QKF, WVF, WOF, counts, nkey);
    hipLaunchKernelGGL((k_mgemm<unsigned short, true>), dim3(gemmVBlocks + histBlocks),
                       dim3(256), 0, stream,
                       node_feature, WVF, (const float*)nullptr, Vb, lk, QKF, Nn,
                       edge_dst, scale_id, counts, done, offsets, cursor,
                       E, NQr, nkey, histBlocks);
    hipLaunchKernelGGL(k_scatter_edge, dim3((E + 255) / 256), dim3(256), 0, stream,
                       edge_src, edge_dst, scale_id, query_coord, node_coord, lk,
                       Wa, ba, cursor, packed, edP, edG, E, NQr);
    hipLaunchKernelGGL(k_main10, dim3((NQr + 1) / 2), dim3(256), 0, stream,
                       offsets, packed, edP, edG, Vb, bm, WmF, WshF, out_pre, NQr);
    hipLaunchKernelGGL((k_mgemm<float, false>), dim3((NQr + 63) / 64), dim3(256), 0, stream,
                       out_pre, WOF, bo, out, (float*)nullptr, (const short*)nullptr, NQr,
                       (const int*)nullptr, (const int*)nullptr, (int*)nullptr, (int*)nullptr,
                       (int*)nullptr, (int*)nullptr, 0, 0, 0, 0);
}

// Round 19
// 123.501 us; speedup vs baseline: 1.1551x; 1.1551x over previous
//
#include <hip/hip_runtime.h>
#include <hip/hip_bf16.h>
#include <math.h>

#define PI_F 3.14159265358979323846f

typedef __attribute__((ext_vector_type(8))) short short8v;   // 8 bf16 (4 VGPR)
typedef __attribute__((ext_vector_type(4))) float f32x4;

__device__ __forceinline__ short f2bf(float x) {
    return __builtin_bit_cast(short, __float2bfloat16(x));
}
__device__ __forceinline__ float bf2f(unsigned short u) {
    return __uint_as_float(((unsigned)u) << 16);
}
__device__ __forceinline__ int pack_bf2(float a, float b) {
    return (int)(unsigned short)f2bf(a) | ((int)(unsigned short)f2bf(b) << 16);
}

// ---------------- workspace layout (float slots) — round-13 proven ----------------
static const size_t WS_WA     = 0;        // [2][64][4] f32
static const size_t WS_BA     = 512;      // [2][4] f32
static const size_t WS_BM     = 520;      // [2][128] f32
static const size_t WS_WMF    = 776;      // [2][8][2][64][8] bf16 = 16384
static const size_t WS_WSHF   = 8968;     // [8][64][8] bf16 = 4096
static const size_t WS_QKF    = 11016;    // [4][64][8] bf16 = 2048
static const size_t WS_WVF    = 12040;    // [4][8][64][8] bf16 = 16384
static const size_t WS_WOF    = 20232;    // [4][8][64][8] bf16 = 16384
static const size_t WS_COUNTS = 28424;    // [8192] int
static const size_t WS_OFFS   = 36624;    // [8193] int (+pad)
static const size_t WS_CURSOR = 44824;    // [8192] int
static const size_t WS_PACKED = 53016;    // [E] int (src | dst<<16)
static const size_t WS_LK     = 315160;   // [N][4] f32
static const size_t WS_EDP    = 479000;   // [E][4] f32 {p0..p3}
static const size_t WS_EDG    = 1527576;  // [E][4] f32 {ux,uy,uz,xn}
static const size_t WS_VB     = 2576152;  // [N][128] bf16
static const size_t WS_OUTPRE = 5197592;  // [NQ][128] f32
// end 5721880 slots = 22.89 MB (proven in rounds 6-7, 10, 13, 17)

// ---------------------------------------------------------------
// Block 0: fold QK/Wa/ba/bm, emit QKF frags.
// Blocks 1..208: format WmF / WshF / WVF / WOF fragments.
// Blocks 209..240: zero counts (replaces in-graph hipMemsetAsync).
// B-frag column permutation: physical col c = (lane&15)*8 + ct.
__global__ __launch_bounds__(256) void k_prepfmt(
    const float* b_dst, const float* Wq, const float* Wk,
    const float* W_rad0, const float* b_rad0,
    const float* W_rad1, const float* b_rad1,
    const float* W_msg, const float* W_alpha, const float* Wv,
    const float* Wo, const float* W_sh,
    float* Wa, float* ba, float* bm,
    short* WmF, short* WshF, short* QKF, short* WVF, short* WOF,
    int* counts, int nkey) {
    __shared__ float qs_s[128];
    __shared__ float qk_s[512];
    int t = threadIdx.x;
    int b = blockIdx.x;
    if (b == 0) {
        if (t < 128) {
            float acc = 0.f;
            for (int c = 0; c < 128; ++c) acc += b_dst[c] * Wq[c * 128 + t];
            qs_s[t] = acc;
        }
        __syncthreads();
        if (t < 128) {
            const float invs = 0.17677669529663687f; // 1/sqrt(32)
            for (int h = 0; h < 4; ++h) {
                float acc = 0.f;
                for (int d = 0; d < 32; ++d)
                    acc += Wk[t * 128 + h * 32 + d] * qs_s[h * 32 + d];
                qk_s[t * 4 + h] = acc * invs;
            }
        }
        for (int idx = t; idx < 512; idx += 256) {
            int s = idx >> 8, i = (idx >> 2) & 63, h = idx & 3;
            const float* Wr = s ? W_rad1 : W_rad0;
            float acc = 0.f;
            for (int u = 0; u < 64; ++u) acc += Wr[i * 64 + u] * W_alpha[u * 4 + h];
            Wa[idx] = acc;
        }
        if (t < 8) {
            int s = t >> 2, h = t & 3;
            const float* br = s ? b_rad1 : b_rad0;
            float acc = 0.f;
            for (int u = 0; u < 64; ++u) acc += br[u] * W_alpha[u * 4 + h];
            ba[t] = acc;
        }
        {
            int s = t >> 7, c = t & 127;
            const float* br = s ? b_rad1 : b_rad0;
            float acc = 0.f;
            for (int u = 0; u < 64; ++u) acc += br[u] * W_msg[u * 128 + c];
            bm[t] = acc;
        }
        __syncthreads();
        for (int idx = t; idx < 2048; idx += 256) {
            int j = idx & 7, lane = (idx >> 3) & 63, kh = idx >> 9;
            int k = kh * 32 + ((lane >> 4) << 3) + j;
            int col = lane & 15;
            QKF[idx] = f2bf(col < 4 ? qk_s[k * 4 + col] : 0.f);
        }
    } else if (b <= 208) {
        int item = (b - 1) * 256 + t;   // 0..53247
        if (item < 16384) {
            int j = item & 7, lane = (item >> 3) & 63, kh = (item >> 9) & 1;
            int ct = (item >> 10) & 7, sid = item >> 13;
            int k = kh * 32 + ((lane >> 4) << 3) + j;
            int c = (lane & 15) * 8 + ct;        // permuted
            const float* Wr = sid ? W_rad1 : W_rad0;
            float acc = 0.f;
            for (int u = 0; u < 64; ++u) acc += Wr[k * 64 + u] * W_msg[u * 128 + c];
            WmF[item] = f2bf(acc);
        } else if (item < 20480) {
            int i2 = item - 16384;
            int j = i2 & 7, lane = (i2 >> 3) & 63, ct = (i2 >> 9) & 7;
            int k = ((lane >> 4) << 3) + j;
            int c = (lane & 15) * 8 + ct;        // permuted
            WshF[i2] = f2bf(k < 9 ? W_sh[k * 128 + c] : 0.f);
        } else if (item < 36864) {
            int i2 = item - 20480;   // [kh][ct][lane][j]
            int j = i2 & 7, lane = (i2 >> 3) & 63, ct = (i2 >> 9) & 7, kh = (i2 >> 12) & 3;
            int k = kh * 32 + ((lane >> 4) << 3) + j;
            int c = (lane & 15) * 8 + ct;        // permuted
            WVF[i2] = f2bf(Wv[k * 128 + c]);
        } else {
            int i2 = item - 36864;
            int j = i2 & 7, lane = (i2 >> 3) & 63, ct = (i2 >> 9) & 7, kh = (i2 >> 12) & 3;
            int k = kh * 32 + ((lane >> 4) << 3) + j;
            int c = (lane & 15) * 8 + ct;        // permuted
            WOF[i2] = f2bf(Wo[k * 128 + c]);
        }
    } else {
        int idx = (b - 209) * 256 + t;
        if (idx < nkey) counts[idx] = 0;
    }
}

// ---------------------------------------------------------------
// MFMA GEMM with permuted B: out[row][m*8+ct]; vectorized stores.
// Optional lk = A @ QK. Blocks past the GEMM grid run the edge histogram
// (counts zeroed by k_prepfmt, which precedes this launch).
template <typename OUT, bool LK>
__global__ __launch_bounds__(256) void k_mgemm(
    const float* A, const short* WF, const float* bias, OUT* out,
    float* lk, const short* QKF, int M,
    const int* edge_dst, const int* scale_id, int* counts, int E, int NQr) {
    int gb = (M + 63) >> 6;            // GEMM blocks
    if ((int)blockIdx.x >= gb) {
        int e = ((int)blockIdx.x - gb) * 256 + (int)threadIdx.x;
        if (e < E) atomicAdd(&counts[scale_id[e] * NQr + edge_dst[e]], 1);
        return;
    }
    int t = threadIdx.x;
    int w = t >> 6, lane = t & 63;
    int m = lane & 15, grp = lane >> 4;
    int row0 = (blockIdx.x * 4 + w) * 16;
    if (row0 >= M) return;

    short8v a[4];
#pragma unroll
    for (int kh = 0; kh < 4; ++kh) {
        const float* ap = &A[(size_t)(row0 + m) * 128 + kh * 32 + grp * 8];
        float4 f0 = *(const float4*)ap;
        float4 f1 = *(const float4*)(ap + 4);
        a[kh][0] = f2bf(f0.x); a[kh][1] = f2bf(f0.y);
        a[kh][2] = f2bf(f0.z); a[kh][3] = f2bf(f0.w);
        a[kh][4] = f2bf(f1.x); a[kh][5] = f2bf(f1.y);
        a[kh][6] = f2bf(f1.z); a[kh][7] = f2bf(f1.w);
    }
    if constexpr (LK) {
        f32x4 cl = {0.f, 0.f, 0.f, 0.f};
#pragma unroll
        for (int kh = 0; kh < 4; ++kh) {
            short8v qb = *(const short8v*)&QKF[(kh * 64 + lane) * 8];
            cl = __builtin_amdgcn_mfma_f32_16x16x32_bf16(a[kh], qb, cl, 0, 0, 0);
        }
        if (m < 4) {
#pragma unroll
            for (int r = 0; r < 4; ++r)
                lk[(size_t)(row0 + grp * 4 + r) * 4 + m] = cl[r];
        }
    }
    f32x4 c8[8];
#pragma unroll
    for (int ct = 0; ct < 8; ++ct) {
        f32x4 c = {0.f, 0.f, 0.f, 0.f};
#pragma unroll
        for (int kh = 0; kh < 4; ++kh) {
            short8v bf = *(const short8v*)&WF[((kh * 8 + ct) * 64 + lane) * 8];
            c = __builtin_amdgcn_mfma_f32_16x16x32_bf16(a[kh], bf, c, 0, 0, 0);
        }
        c8[ct] = c;
    }
    if constexpr (sizeof(OUT) == 2) {
#pragma unroll
        for (int r = 0; r < 4; ++r) {
            int row = row0 + grp * 4 + r;
            int4 sv;
            sv.x = pack_bf2(c8[0][r], c8[1][r]);
            sv.y = pack_bf2(c8[2][r], c8[3][r]);
            sv.z = pack_bf2(c8[4][r], c8[5][r]);
            sv.w = pack_bf2(c8[6][r], c8[7][r]);
            *(int4*)&out[(size_t)row * 128 + m * 8] = sv;
        }
    } else {
        float4 b0 = make_float4(0.f, 0.f, 0.f, 0.f), b1 = b0;
        if (bias) {
            b0 = *(const float4*)&bias[m * 8];
            b1 = *(const float4*)&bias[m * 8 + 4];
        }
#pragma unroll
        for (int r = 0; r < 4; ++r) {
            int row = row0 + grp * 4 + r;
            float4 o0 = make_float4(c8[0][r] + b0.x, c8[1][r] + b0.y,
                                    c8[2][r] + b0.z, c8[3][r] + b0.w);
            float4 o1 = make_float4(c8[4][r] + b1.x, c8[5][r] + b1.y,
                                    c8[6][r] + b1.z, c8[7][r] + b1.w);
            *(float4*)&out[(size_t)row * 128 + m * 8] = o0;
            *(float4*)&out[(size_t)row * 128 + m * 8 + 4] = o1;
        }
    }
}

// ---------------------------------------------------------------
// single-block exclusive scan; writes offsets[nkey+1] and cursor copy
__global__ void k_scan(const int* counts, int* offsets, int* cursor, int nkey) {
    __shared__ int sdata[256];
    int t = threadIdx.x;
    int chunk = (nkey + 255) / 256;
    int sum = 0;
    for (int i = 0; i < chunk; ++i) {
        int idx = t * chunk + i;
        sum += (idx < nkey) ? counts[idx] : 0;
    }
    sdata[t] = sum;
    __syncthreads();
    for (int off = 1; off < 256; off <<= 1) {
        int v = (t >= off) ? sdata[t - off] : 0;
        __syncthreads();
        sdata[t] += v;
        __syncthreads();
    }
    int run = sdata[t] - sum;
    for (int i = 0; i < chunk; ++i) {
        int idx = t * chunk + i;
        if (idx < nkey) {
            offsets[idx] = run;
            cursor[idx] = run;
            run += counts[idx];
        }
    }
    if (t == 255) offsets[nkey] = sdata[255];
}

// ---------------------------------------------------------------
// Fused scatter + per-edge geometry/softmax-numerator pass.
__global__ __launch_bounds__(256) void k_scatter_edge(
    const int* edge_src, const int* edge_dst, const int* scale_id,
    const float* qc, const float* nc, const float* lk,
    const float* WaB, const float* baB, int* cursor,
    int* packed, float* edP, float* edG, int E, int NQr) {
    __shared__ float WaS[512];
    __shared__ float baS[8];
    int t = threadIdx.x;
    for (int i = t; i < 512; i += 256) WaS[i] = WaB[i];
    if (t < 8) baS[t] = baB[t];
    __syncthreads();
    int e = blockIdx.x * 256 + t;
    if (e >= E) return;
    int src = edge_src[e], dst = edge_dst[e], sid = scale_id[e];
    int pos = atomicAdd(&cursor[sid * NQr + dst], 1);

    float qx = qc[dst * 3 + 0], qy = qc[dst * 3 + 1], qz = qc[dst * 3 + 2];
    float vx = nc[src * 3 + 0] - qx;
    float vy = nc[src * 3 + 1] - qy;
    float vz = nc[src * 3 + 2] - qz;
    float r = sqrtf(vx * vx + vy * vy + vz * vz + 1e-12f);
    float rinv = 1.0f / r;
    float ux = vx * rinv, uy = vy * rinv, uz = vz * rinv;

    float roff = sid ? 0.2f : 0.1f;
    float rdiv = sid ? (1.0f / 3.8f) : (1.0f / 1.9f);
    float xn = (r - roff) * rdiv;
    float su = fminf(fmaxf((xn - 0.8f) * 5.0f, 0.0f), 1.0f);
    float soft = 0.5f * (1.0f + __cosf(PI_F * su));

    float4 lkv = *(const float4*)&lk[(size_t)src * 4];

    const float qs = 64.f / 63.f;
    const float Qc = __expf(-qs * qs);
    const float* Wrow = WaS + sid * 256;
    float a0 = 0.f, a1 = 0.f, a2 = 0.f, a3 = 0.f;
#pragma unroll
    for (int ch = 0; ch < 8; ++ch) {
        float d = (xn - (float)(ch * 8) * (1.0f / 63.0f)) * 64.0f;
        float g = __expf(-0.5f * d * d);
        float tt = __expf(fminf(qs * d - 0.5f * qs * qs, 60.f));
#pragma unroll
        for (int j = 0; j < 8; ++j) {
            float4 wa = *(const float4*)&Wrow[(ch * 8 + j) * 4];
            a0 = fmaf(g, wa.x, a0);
            a1 = fmaf(g, wa.y, a1);
            a2 = fmaf(g, wa.z, a2);
            a3 = fmaf(g, wa.w, a3);
            g *= tt; tt *= Qc;
        }
    }
    float p0 = __expf(lkv.x + soft * a0 + baS[sid * 4 + 0]);
    float p1 = __expf(lkv.y + soft * a1 + baS[sid * 4 + 1]);
    float p2 = __expf(lkv.z + soft * a2 + baS[sid * 4 + 2]);
    float p3 = __expf(lkv.w + soft * a3 + baS[sid * 4 + 3]);
    packed[pos] = src | (dst << 16);
    *(float4*)&edP[(size_t)pos * 4] = make_float4(p0, p1, p2, p3);
    *(float4*)&edG[(size_t)pos * 4] = make_float4(ux, uy, uz, xn);
}

// ---------------------------------------------------------------
// g-fragment via multiply-chain (2 exp per 8 centers).
__device__ __forceinline__ short8v gchain(float xn, int k0, float soft, float Qc) {
    const float qs = 64.f / 63.f;
    float d = (xn - (float)k0 * (1.0f / 63.0f)) * 64.0f;
    float g = __expf(-0.5f * d * d);
    float tt = __expf(fminf(qs * d - 0.5f * qs * qs, 60.f));
    short8v rr;
#pragma unroll
    for (int j = 0; j < 8; ++j) {
        rr[j] = f2bf(g * soft);
        g *= tt; tt *= Qc;
    }
    return rr;
}

// MFMA edge aggregation: one WAVE per (dst,sid) key, 2-stage pipeline
// (packed/edP/edG two tiles ahead; V one tile ahead). The two sid-waves of
// a dst share a block and combine via one LDS pair-sum. Grid = NQ/2.
__global__ __launch_bounds__(256) void k_main10(
    const int* offsets, const int* packed, const float* edP, const float* edG,
    const unsigned short* Vu, const float* bm, const short* WmF, const short* WshF,
    float* out_pre, int NQr) {
    __shared__ float part[4][132];
    int t = threadIdx.x;
    int w = t >> 6, lane = t & 63;
    int sid = w & 1;
    int dst = blockIdx.x * 2 + (w >> 1);
    int m = lane & 15, grp = lane >> 4;
    int h = m >> 2;

    int key = sid * NQr + dst;
    int s0 = offsets[key], s1 = offsets[key + 1];
    int nt = (s1 - s0 + 15) >> 4;

    float acc[8];
#pragma unroll
    for (int i = 0; i < 8; ++i) acc[i] = 0.f;
    float den = 0.f;

    float4 bm0 = *(const float4*)&bm[sid * 128 + m * 8];
    float4 bm1 = *(const float4*)&bm[sid * 128 + m * 8 + 4];
    float bmv[8] = {bm0.x, bm0.y, bm0.z, bm0.w, bm1.x, bm1.y, bm1.z, bm1.w};
    const short* wmp = WmF + sid * 8192;

    const float qs = 64.f / 63.f;
    const float Qc = __expf(-qs * qs);
    const float s3 = 1.7320508075688772f, s15 = 3.872983346207417f, s5 = 2.23606797749979f;

    if (nt > 0) {
        auto loadA = [&](int tl, int (&srcs)[4], float (&ph)[4], float4& G4) {
            int q0 = s0 + tl * 16;
            int posA = q0 + m; if (posA >= s1) posA = s1 - 1;
            G4 = *(const float4*)&edG[(size_t)posA * 4];
#pragma unroll
            for (int r = 0; r < 4; ++r) {
                int pos = q0 + grp * 4 + r;
                bool valid = pos < s1;
                if (!valid) pos = s1 - 1;
                srcs[r] = packed[pos] & 0xFFFF;
                float p = edP[(size_t)pos * 4 + h];
                ph[r] = valid ? p : 0.f;
            }
        };
        auto loadV = [&](const int (&srcs)[4], int4 (&vv)[4]) {
#pragma unroll
            for (int r = 0; r < 4; ++r)
                vv[r] = *(const int4*)&Vu[(size_t)srcs[r] * 128 + m * 8];
        };

        int srcsA[4], srcsB[4], srcsC[4];
        float phA[4], phB[4], phC[4];
        float4 gA, gB, gC;
        int4 vA[4], vB[4];

        loadA(0, srcsA, phA, gA);
        loadV(srcsA, vA);
        if (nt > 1) loadA(1, srcsB, phB, gB);

        for (int tl = 0; tl < nt; ++tl) {
            if (tl + 1 < nt) loadV(srcsB, vB);
            if (tl + 2 < nt) loadA(tl + 2, srcsC, phC, gC);

            // ---- compute current tile ----
            int wds[4][4];
#pragma unroll
            for (int r = 0; r < 4; ++r) {
                wds[r][0] = vA[r].x; wds[r][1] = vA[r].y;
                wds[r][2] = vA[r].z; wds[r][3] = vA[r].w;
            }
            den += phA[0] + phA[1] + phA[2] + phA[3];

            float xn = gA.w;
            float su = fminf(fmaxf((xn - 0.8f) * 5.0f, 0.0f), 1.0f);
            float soft = 0.5f * (1.0f + __cosf(PI_F * su));
            short8v aG0 = gchain(xn, grp * 8, soft, Qc);
            short8v aG1 = gchain(xn, 32 + grp * 8, soft, Qc);

            float ux = gA.x, uy = gA.y, uz = gA.z;
            float sh[9];
            sh[0] = 1.f; sh[1] = s3 * ux; sh[2] = s3 * uy; sh[3] = s3 * uz;
            sh[4] = s15 * ux * uy; sh[5] = s15 * uy * uz;
            sh[6] = 0.5f * s5 * (3.f * uz * uz - 1.f);
            sh[7] = s15 * ux * uz; sh[8] = 0.5f * s15 * (ux * ux - uy * uy);
            short8v aS;
#pragma unroll
            for (int j = 0; j < 8; ++j) {
                float v = (grp == 0) ? sh[j] : ((grp == 1 && j == 0) ? sh[8] : 0.f);
                aS[j] = f2bf(v);
            }

#pragma unroll
            for (int ct = 0; ct < 8; ++ct) {
                short8v b0 = *(const short8v*)&wmp[((ct * 2 + 0) * 64 + lane) * 8];
                short8v b1 = *(const short8v*)&wmp[((ct * 2 + 1) * 64 + lane) * 8];
                short8v bS = *(const short8v*)&WshF[(ct * 64 + lane) * 8];
                f32x4 cms = {bmv[ct], bmv[ct], bmv[ct], bmv[ct]};   // seed with bm
                cms = __builtin_amdgcn_mfma_f32_16x16x32_bf16(aG0, b0, cms, 0, 0, 0);
                cms = __builtin_amdgcn_mfma_f32_16x16x32_bf16(aG1, b1, cms, 0, 0, 0);
                f32x4 csh = {0.f, 0.f, 0.f, 0.f};
                csh = __builtin_amdgcn_mfma_f32_16x16x32_bf16(aS, bS, csh, 0, 0, 0);
#pragma unroll
                for (int r = 0; r < 4; ++r) {
                    int wd = wds[r][ct >> 1];
                    unsigned short vu = (ct & 1) ? (unsigned short)(wd >> 16)
                                                 : (unsigned short)(wd & 0xFFFF);
                    float vf = bf2f(vu);
                    float ve = fmaf(vf, cms[r], csh[r]);
                    acc[ct] = fmaf(phA[r], ve, acc[ct]);
                }
            }

            // ---- rotate pipeline ----
            gA = gB; gB = gC;
#pragma unroll
            for (int r = 0; r < 4; ++r) {
                phA[r] = phB[r]; phB[r] = phC[r];
                srcsB[r] = srcsC[r];
                vA[r] = vB[r];
            }
        }
    }

    // ---- reduce over grp within wave ----
#pragma unroll
    for (int i = 0; i < 8; ++i) {
        acc[i] += __shfl_xor(acc[i], 16);
        acc[i] += __shfl_xor(acc[i], 32);
    }
    den += __shfl_xor(den, 16);
    den += __shfl_xor(den, 32);
    if (lane < 16) {
#pragma unroll
        for (int ct = 0; ct < 8; ++ct) part[w][m * 8 + ct] = acc[ct];
        if ((m & 3) == 0) part[w][128 + h] = den;
    }
    __syncthreads();

    // ---- combine the two sid-waves of each dst, divide, store ----
    {
        int which = t >> 7;
        int col = t & 127;
        int d2 = blockIdx.x * 2 + which;
        if (d2 < NQr) {
            int hh = col >> 5;
            float s = part[2 * which][col] + part[2 * which + 1][col];
            float d = part[2 * which][128 + hh] + part[2 * which + 1][128 + hh];
            out_pre[(size_t)d2 * 128 + col] = s / (d + 1e-9f);
        }
    }
}

// ---------------------------------------------------------------
extern "C" void kernel_launch(void* const* d_in, const int* in_sizes, int n_in,
                              void* d_out, int out_size, void* d_ws, size_t ws_size,
                              hipStream_t stream) {
    const float* query_coord = (const float*)d_in[0];
    const float* node_feature = (const float*)d_in[1];
    const float* node_coord = (const float*)d_in[2];
    const int* edge_src = (const int*)d_in[3];
    const int* edge_dst = (const int*)d_in[4];
    const int* scale_id = (const int*)d_in[5];
    const float* b_dst = (const float*)d_in[6];
    const float* Wq = (const float*)d_in[7];
    const float* Wk = (const float*)d_in[8];
    const float* Wv = (const float*)d_in[9];
    const float* Wo = (const float*)d_in[10];
    const float* bo = (const float*)d_in[11];
    const float* W_rad0 = (const float*)d_in[12];
    const float* b_rad0 = (const float*)d_in[13];
    const float* W_rad1 = (const float*)d_in[14];
    const float* b_rad1 = (const float*)d_in[15];
    const float* W_msg = (const float*)d_in[16];
    const float* W_sh = (const float*)d_in[17];
    const float* W_alpha = (const float*)d_in[18];
    (void)n_in; (void)ws_size; (void)out_size;

    int NQr = in_sizes[0] / 3;      // 4096
    int Nn = in_sizes[1] / 128;     // 40960
    int E = in_sizes[3];            // 262144
    int nkey = NQr * 2;

    float* ws = (float*)d_ws;
    float* Wa = ws + WS_WA;
    float* ba = ws + WS_BA;
    float* bm = ws + WS_BM;
    short* WmF = (short*)(ws + WS_WMF);
    short* WshF = (short*)(ws + WS_WSHF);
    short* QKF = (short*)(ws + WS_QKF);
    short* WVF = (short*)(ws + WS_WVF);
    short* WOF = (short*)(ws + WS_WOF);
    int* counts = (int*)(ws + WS_COUNTS);
    int* offsets = (int*)(ws + WS_OFFS);
    int* cursor = (int*)(ws + WS_CURSOR);
    int* packed = (int*)(ws + WS_PACKED);
    float* lk = ws + WS_LK;
    float* edP = ws + WS_EDP;
    float* edG = ws + WS_EDG;
    unsigned short* Vb = (unsigned short*)(ws + WS_VB);
    float* out_pre = ws + WS_OUTPRE;
    float* out = (float*)d_out;

    int zeroBlocks = (nkey + 255) / 256;            // 32
    int histBlocks = (E + 255) / 256;               // 1024
    int gemmVBlocks = (Nn + 63) / 64;               // 640
    hipLaunchKernelGGL(k_prepfmt, dim3(209 + zeroBlocks), dim3(256), 0, stream,
                       b_dst, Wq, Wk, W_rad0, b_rad0, W_rad1, b_rad1, W_msg, W_alpha,
                       Wv, Wo, W_sh, Wa, ba, bm, WmF, WshF, QKF, WVF, WOF, counts, nkey);
    hipLaunchKernelGGL((k_mgemm<unsigned short, true>), dim3(gemmVBlocks + histBlocks),
                       dim3(256), 0, stream,
                       node_feature, WVF, (const float*)nullptr, Vb, lk, QKF, Nn,
                       edge_dst, scale_id, counts, E, NQr);
    hipLaunchKernelGGL(k_scan, dim3(1), dim3(256), 0, stream, counts, offsets, cursor, nkey);
    hipLaunchKernelGGL(k_scatter_edge, dim3((E + 255) / 256), dim3(256), 0, stream,
                       edge_src, edge_dst, scale_id, query_coord, node_coord, lk,
                       Wa, ba, cursor, packed, edP, edG, E, NQr);
    hipLaunchKernelGGL(k_main10, dim3((NQr + 1) / 2), dim3(256), 0, stream,
                       offsets, packed, edP, edG, Vb, bm, WmF, WshF, out_pre, NQr);
    hipLaunchKernelGGL((k_mgemm<float, false>), dim3((NQr + 63) / 64), dim3(256), 0, stream,
                       out_pre, WOF, bo, out, (float*)nullptr, (const short*)nullptr, NQr,
                       (const int*)nullptr, (const int*)nullptr, (int*)nullptr, 0, 0);
}